// Round 6
// baseline (590.201 us; speedup 1.0000x reference)
//
#include <hip/hip_runtime.h>
#include <hip/hip_bf16.h>
#include <float.h>

#define BB 64
#define NN 900
#define CC 91
#define MM 128
#define BIG 1e18
#define NSLOT 15              // 15*64 = 960 >= 900 columns per lane-slot grid
#define LAST_VALID 4          // slot 14 valid for lanes 0..3 (896+lane < 900)
#define TPB_C 128

// ---------------------------------------------------------------------------
// Kernel 1: cost matrix, stored TRANSPOSED as costT[b][t (M)][p (N)] f32.
// Unchanged from round-3/5 passing version.
// ---------------------------------------------------------------------------
__global__ __launch_bounds__(TPB_C) void cost_kernel(
    const float* __restrict__ logits,   // [B,N,C]
    const float* __restrict__ boxes,    // [B,N,4]
    const int*   __restrict__ tlabels,  // [B,M]
    const float* __restrict__ tboxes,   // [B,M,4]
    float* __restrict__ costT)          // [B,M,N]
{
    const int b   = blockIdx.y;
    const int p0  = blockIdx.x * TPB_C;
    const int cnt = min(TPB_C, NN - p0);
    const int tid = threadIdx.x;

    __shared__ float s_lg[TPB_C * CC];   // 46592 B
    __shared__ float s_tb[MM][4];
    __shared__ int   s_tl[MM];

    {
        s_tl[tid] = tlabels[b * MM + tid];
        const float4 tb4 = ((const float4*)tboxes)[(size_t)b * MM + tid];
        s_tb[tid][0] = tb4.x; s_tb[tid][1] = tb4.y;
        s_tb[tid][2] = tb4.z; s_tb[tid][3] = tb4.w;
    }
    {
        const float* gbase = logits + ((size_t)b * NN + p0) * CC;
        const int total = cnt * CC;
        const int n4 = total >> 2;
        for (int k = tid; k < n4; k += TPB_C)
            ((float4*)s_lg)[k] = ((const float4*)gbase)[k];
        for (int k = (n4 << 2) + tid; k < total; k += TPB_C)
            s_lg[k] = gbase[k];
    }
    __syncthreads();
    if (tid >= cnt) return;

    const float* lg = s_lg + tid * CC;
    float mx = -INFINITY;
    for (int c = 0; c < CC; ++c) mx = fmaxf(mx, lg[c]);
    float ssum = 0.f;
    for (int c = 0; c < CC; ++c) ssum += expf(lg[c] - mx);

    const float4 bx4 = ((const float4*)boxes)[(size_t)b * NN + p0 + tid];
    const float cx = bx4.x, cy = bx4.y, w = bx4.z, h = bx4.w;
    const float px0 = cx - 0.5f * w, py0 = cy - 0.5f * h;
    const float px1 = cx + 0.5f * w, py1 = cy + 0.5f * h;
    const float parea = (px1 - px0) * (py1 - py0);

    float* outp = costT + (size_t)b * MM * NN + p0 + tid;
    for (int j = 0; j < MM; ++j) {
        const float tcx = s_tb[j][0], tcy = s_tb[j][1], tw = s_tb[j][2], th = s_tb[j][3];
        float l1 = ((fabsf(cx - tcx) + fabsf(cy - tcy)) + fabsf(w - tw)) + fabsf(h - th);
        const float tx0 = tcx - 0.5f * tw, ty0 = tcy - 0.5f * th;
        const float tx1 = tcx + 0.5f * tw, ty1 = tcy + 0.5f * th;
        float iw = fminf(px1, tx1) - fmaxf(px0, tx0); iw = fmaxf(iw, 0.f);
        float ih = fminf(py1, ty1) - fmaxf(py0, ty0); ih = fmaxf(ih, 0.f);
        const float inter = iw * ih;
        const float tarea = (tx1 - tx0) * (ty1 - ty0);
        const float uni   = parea + tarea - inter;
        const float iou   = inter / (uni + 1e-6f);
        const float enc   = (fmaxf(px1, tx1) - fminf(px0, tx0)) *
                            (fmaxf(py1, ty1) - fminf(py0, ty0)) + 1e-6f;
        const float giou  = iou - (enc - uni) / enc;
        const float pcls  = expf(lg[s_tl[j]] - mx) / ssum;
        const float cost  = (1.0f * (-pcls) + 5.0f * l1) + 2.0f * (-giou);
        outp[(size_t)j * NN] = cost;
    }
}

// ---------------------------------------------------------------------------
// Kernel 2: JV LSA, one wave per batch. Round-6 changes:
//  - L2 prefetch of the whole batch slab at start (460KB -> local XCD L2)
//  - tournament-tree per-lane argmin fold (depth 4, left/ascending-j ties)
//  - p[best j] tracked through the fold -> p[j1] via shuffle, not LDS
//  All f64 arithmetic, update order, and tie-break semantics unchanged.
// ---------------------------------------------------------------------------
__global__ __launch_bounds__(64) void lsa_kernel(
    const float* __restrict__ costT,  // [B,M,N]
    int* __restrict__ out)            // rows [B,M] then cols [B,M], int32
{
    const int b    = blockIdx.x;
    const int lane = threadIdx.x;

    __shared__ double s_u[MM + 1];
    __shared__ int    s_p[NN + 1];
    __shared__ int    s_way[NN + 1];
    __shared__ int    s_c4r[MM];

    double v[NSLOT], minv[NSLOT];
    int    preg[NSLOT];
    float  cv[NSLOT];

    for (int j = lane; j <= NN; j += 64) s_p[j] = 0;
    for (int i = lane; i <= MM; i += 64) s_u[i] = 0.0;
    #pragma unroll
    for (int s = 0; s < NSLOT; ++s) { v[s] = 0.0; preg[s] = 0; }
    __syncthreads();

    const float* cb = costT + (size_t)b * MM * NN;

    // ---- L2 prefetch: stream the batch slab (115200 floats) into this
    // XCD's L2. Accumulator keeps loads live; loads pipeline under the
    // dependent-fadd chain.
    {
        const float4* cb4 = (const float4*)cb;
        float acc = 0.f;
        for (int k = lane; k < (MM * NN) / 4; k += 64) {
            const float4 t = cb4[k];
            acc += t.x + t.y + t.z + t.w;
        }
        asm volatile("" :: "v"(acc));   // keep-alive, no DCE (rule #17)
    }

    // prefetch row 0 (Dijkstra i=1) — now L2-hot
    #pragma unroll
    for (int s = 0; s < NSLOT; ++s) {
        const bool valid = (s < NSLOT - 1) || (lane < LAST_VALID);
        cv[s] = valid ? cb[s * 64 + lane] : 0.f;
    }

    for (int i = 1; i <= MM; ++i) {
        unsigned used_mask = 0;
        #pragma unroll
        for (int s = 0; s < NSLOT; ++s) minv[s] = BIG;
        if (lane == 0) s_p[0] = i;
        int j0 = 0;
        double ui0 = 0.0;   // u[i] == 0: fresh row never touched before

        while (true) {
            // mark j0 used (column 0 is virtual)
            if (j0 > 0) {
                const int jp = j0 - 1;
                if ((jp & 63) == lane) used_mask |= 1u << (jp >> 6);
            }

            // ---- scan: update minv/way, build per-slot candidates
            double cnd[NSLOT];
            #pragma unroll
            for (int s = 0; s < NSLOT; ++s) {
                const bool valid = (s < NSLOT - 1) || (lane < LAST_VALID);
                const bool fr = valid && !((used_mask >> s) & 1u);
                const double cur = (double)cv[s] - ui0 - v[s];
                if (fr && cur < minv[s]) { minv[s] = cur; s_way[s * 64 + lane + 1] = j0; }
                cnd[s] = fr ? minv[s] : BIG;
            }
            // ---- tournament tree (depth 4), left (= smaller j) wins ties
            double n1v[8]; int n1j[8], n1p[8];
            #pragma unroll
            for (int s = 0; s < 8; ++s) {
                const int a = 2 * s, bb2 = 2 * s + 1;
                double va = cnd[a]; int ja = a * 64 + lane + 1; int pa = preg[a];
                if (bb2 < NSLOT) {
                    if (cnd[bb2] < va) { va = cnd[bb2]; ja = bb2 * 64 + lane + 1; pa = preg[bb2]; }
                }
                n1v[s] = va; n1j[s] = ja; n1p[s] = pa;
            }
            double n2v[4]; int n2j[4], n2p[4];
            #pragma unroll
            for (int s = 0; s < 4; ++s) {
                double va = n1v[2*s]; int ja = n1j[2*s]; int pa = n1p[2*s];
                if (n1v[2*s+1] < va) { va = n1v[2*s+1]; ja = n1j[2*s+1]; pa = n1p[2*s+1]; }
                n2v[s] = va; n2j[s] = ja; n2p[s] = pa;
            }
            double n3v[2]; int n3j[2], n3p[2];
            #pragma unroll
            for (int s = 0; s < 2; ++s) {
                double va = n2v[2*s]; int ja = n2j[2*s]; int pa = n2p[2*s];
                if (n2v[2*s+1] < va) { va = n2v[2*s+1]; ja = n2j[2*s+1]; pa = n2p[2*s+1]; }
                n3v[s] = va; n3j[s] = ja; n3p[s] = pa;
            }
            double bv = n3v[0]; int bj = n3j[0]; int bp = n3p[0];
            if (n3v[1] < bv) { bv = n3v[1]; bj = n3j[1]; bp = n3p[1]; }

            // ---- cross-lane: sortable-u64 key min (+0.0 normalizes -0)
            const double bvn = bv + 0.0;
            const long long xb = __double_as_longlong(bvn);
            const unsigned long long mykey =
                (xb < 0) ? ~(unsigned long long)xb
                         : ((unsigned long long)xb | 0x8000000000000000ULL);
            unsigned long long kmin = mykey;
            #pragma unroll
            for (int m = 1; m < 64; m <<= 1) {
                const unsigned long long ok = __shfl_xor(kmin, m);
                if (ok < kmin) kmin = ok;
            }
            const unsigned long long inv =
                (kmin & 0x8000000000000000ULL) ? (kmin ^ 0x8000000000000000ULL) : ~kmin;
            const double delta = __longlong_as_double((long long)inv);

            // ---- j1 and p[j1] via broadcast (no LDS on the chain)
            const unsigned long long tied = __ballot(mykey == kmin);
            int j1, pj1;
            if (__builtin_popcountll(tied) == 1) {
                const int src = (int)__builtin_ctzll(tied);
                j1  = __shfl(bj, src);
                pj1 = __shfl(bp, src);
            } else {
                int cand = (mykey == kmin) ? bj : 0x7fffffff;
                #pragma unroll
                for (int m = 1; m < 64; m <<= 1) {
                    const int oc = __shfl_xor(cand, m);
                    if (oc < cand) cand = oc;
                }
                j1 = cand;
                const unsigned long long own = __ballot(mykey == kmin && bj == j1);
                pj1 = __shfl(bp, (int)__builtin_ctzll(own));
            }

            // issue next-row loads ASAP; s_u read + updates hide under them
            double ui_next = 0.0;
            if (pj1 != 0) {
                const float* crow = cb + (size_t)(pj1 - 1) * NN;
                #pragma unroll
                for (int s = 0; s < NSLOT; ++s) {
                    const bool valid = (s < NSLOT - 1) || (lane < LAST_VALID);
                    if (valid) cv[s] = crow[s * 64 + lane];
                }
                ui_next = s_u[pj1];
            }

            // dual updates (sequential-rounding order identical to reference)
            if (lane == 0) s_u[i] += delta;      // u[p[0]] = u[i]
            double uval[NSLOT];
            #pragma unroll
            for (int s = 0; s < NSLOT; ++s) {
                const bool valid = (s < NSLOT - 1) || (lane < LAST_VALID);
                if (valid && ((used_mask >> s) & 1u)) uval[s] = s_u[preg[s]];
            }
            #pragma unroll
            for (int s = 0; s < NSLOT; ++s) {
                const bool valid = (s < NSLOT - 1) || (lane < LAST_VALID);
                if (valid) {
                    if ((used_mask >> s) & 1u) {
                        s_u[preg[s]] = uval[s] + delta;
                        v[s] -= delta;
                    } else {
                        minv[s] -= delta;
                    }
                }
            }

            if (pj1 == 0) {
                if (lane == 0) {                 // augment along 'way' chain
                    int ja = j1;
                    while (ja) {
                        const int jb = s_way[ja];
                        s_p[ja] = s_p[jb];
                        ja = jb;
                    }
                }
                break;
            }
            j0 = j1; ui0 = ui_next;
        }

        // refresh cached p[j] for this lane's columns
        #pragma unroll
        for (int s = 0; s < NSLOT; ++s) {
            const bool valid = (s < NSLOT - 1) || (lane < LAST_VALID);
            if (valid) preg[s] = s_p[s * 64 + lane + 1];
        }
        // prefetch first row of next Dijkstra (cost row index = i, 0-based)
        if (i < MM) {
            const float* crow = cb + (size_t)i * NN;
            #pragma unroll
            for (int s = 0; s < NSLOT; ++s) {
                const bool valid = (s < NSLOT - 1) || (lane < LAST_VALID);
                if (valid) cv[s] = crow[s * 64 + lane];
            }
        }
    }

    // col4row: target t -> matched pred index
    for (int j = 1 + lane; j <= NN; j += 64) {
        const int pj = s_p[j];
        if (pj > 0) s_c4r[pj - 1] = j - 1;
    }
    __syncthreads();

    // transposed return: rows = sorted pred indices, cols = target permutation
    for (int t = lane; t < MM; t += 64) {
        const int val = s_c4r[t];
        int rank = 0;
        for (int q = 0; q < MM; ++q) rank += (s_c4r[q] < val);
        out[(size_t)b * MM + rank] = val;
        out[(size_t)BB * MM + (size_t)b * MM + rank] = t;
    }
}

extern "C" void kernel_launch(void* const* d_in, const int* in_sizes, int n_in,
                              void* d_out, int out_size, void* d_ws, size_t ws_size,
                              hipStream_t stream) {
    const float* logits  = (const float*)d_in[0];   // [64,900,91] f32
    const float* boxes   = (const float*)d_in[1];   // [64,900,4]  f32
    const int*   tlabels = (const int*)d_in[2];     // [64,128]    i32 (from i64)
    const float* tboxes  = (const float*)d_in[3];   // [64,128,4]  f32
    int*   out   = (int*)d_out;                     // rows[64,128] ++ cols[64,128]
    float* costT = (float*)d_ws;                    // [64,128,900] f32 = 28.1 MB

    dim3 g1((NN + TPB_C - 1) / TPB_C, BB);          // 8 x 64
    cost_kernel<<<g1, TPB_C, 0, stream>>>(logits, boxes, tlabels, tboxes, costT);
    lsa_kernel<<<BB, 64, 0, stream>>>(costT, out);
}

// Round 8
// 472.644 us; speedup vs baseline: 1.2487x; 1.2487x over previous
//
#include <hip/hip_runtime.h>
#include <hip/hip_bf16.h>
#include <float.h>

#define BB 64
#define NN 900
#define CC 91
#define MM 128
#define BIG 1e18
#define NSLOT 15              // 15*64 = 960 >= 900 columns per lane-slot grid
#define LAST_VALID 4          // slot 14 valid for lanes 0..3 (896+lane < 900)
#define TPB_C 128

// ---------------------------------------------------------------------------
// Kernel 1: cost matrix, stored TRANSPOSED as costT[b][t (M)][p (N)] f32.
// Unchanged from round-3/5 passing version.
// ---------------------------------------------------------------------------
__global__ __launch_bounds__(TPB_C) void cost_kernel(
    const float* __restrict__ logits,   // [B,N,C]
    const float* __restrict__ boxes,    // [B,N,4]
    const int*   __restrict__ tlabels,  // [B,M]
    const float* __restrict__ tboxes,   // [B,M,4]
    float* __restrict__ costT)          // [B,M,N]
{
    const int b   = blockIdx.y;
    const int p0  = blockIdx.x * TPB_C;
    const int cnt = min(TPB_C, NN - p0);
    const int tid = threadIdx.x;

    __shared__ float s_lg[TPB_C * CC];   // 46592 B
    __shared__ float s_tb[MM][4];
    __shared__ int   s_tl[MM];

    {
        s_tl[tid] = tlabels[b * MM + tid];
        const float4 tb4 = ((const float4*)tboxes)[(size_t)b * MM + tid];
        s_tb[tid][0] = tb4.x; s_tb[tid][1] = tb4.y;
        s_tb[tid][2] = tb4.z; s_tb[tid][3] = tb4.w;
    }
    {
        const float* gbase = logits + ((size_t)b * NN + p0) * CC;
        const int total = cnt * CC;
        const int n4 = total >> 2;
        for (int k = tid; k < n4; k += TPB_C)
            ((float4*)s_lg)[k] = ((const float4*)gbase)[k];
        for (int k = (n4 << 2) + tid; k < total; k += TPB_C)
            s_lg[k] = gbase[k];
    }
    __syncthreads();
    if (tid >= cnt) return;

    const float* lg = s_lg + tid * CC;
    float mx = -INFINITY;
    for (int c = 0; c < CC; ++c) mx = fmaxf(mx, lg[c]);
    float ssum = 0.f;
    for (int c = 0; c < CC; ++c) ssum += expf(lg[c] - mx);

    const float4 bx4 = ((const float4*)boxes)[(size_t)b * NN + p0 + tid];
    const float cx = bx4.x, cy = bx4.y, w = bx4.z, h = bx4.w;
    const float px0 = cx - 0.5f * w, py0 = cy - 0.5f * h;
    const float px1 = cx + 0.5f * w, py1 = cy + 0.5f * h;
    const float parea = (px1 - px0) * (py1 - py0);

    float* outp = costT + (size_t)b * MM * NN + p0 + tid;
    for (int j = 0; j < MM; ++j) {
        const float tcx = s_tb[j][0], tcy = s_tb[j][1], tw = s_tb[j][2], th = s_tb[j][3];
        float l1 = ((fabsf(cx - tcx) + fabsf(cy - tcy)) + fabsf(w - tw)) + fabsf(h - th);
        const float tx0 = tcx - 0.5f * tw, ty0 = tcy - 0.5f * th;
        const float tx1 = tcx + 0.5f * tw, ty1 = tcy + 0.5f * th;
        float iw = fminf(px1, tx1) - fmaxf(px0, tx0); iw = fmaxf(iw, 0.f);
        float ih = fminf(py1, ty1) - fmaxf(py0, ty0); ih = fmaxf(ih, 0.f);
        const float inter = iw * ih;
        const float tarea = (tx1 - tx0) * (ty1 - ty0);
        const float uni   = parea + tarea - inter;
        const float iou   = inter / (uni + 1e-6f);
        const float enc   = (fmaxf(px1, tx1) - fminf(px0, tx0)) *
                            (fmaxf(py1, ty1) - fminf(py0, ty0)) + 1e-6f;
        const float giou  = iou - (enc - uni) / enc;
        const float pcls  = expf(lg[s_tl[j]] - mx) / ssum;
        const float cost  = (1.0f * (-pcls) + 5.0f * l1) + 2.0f * (-giou);
        outp[(size_t)j * NN] = cost;
    }
}

// ---------------------------------------------------------------------------
// DPP wave-64 min of a sortable u64 key (rocPRIM-style reduce; result valid
// in lane 63; exact compares, associative min => bit-identical to butterfly).
// Template params so the builtin gets literal constants (frontend requires).
// old=self (bound_ctrl=false, src==old) so masked rows keep their own value.
// ---------------------------------------------------------------------------
template<int CTRL, int ROW_MASK>
__device__ __forceinline__ unsigned long long dpp_min_u64(unsigned long long x) {
    const unsigned lo = (unsigned)x, hi = (unsigned)(x >> 32);
    const unsigned plo = (unsigned)__builtin_amdgcn_update_dpp((int)lo, (int)lo, CTRL, ROW_MASK, 0xF, false);
    const unsigned phi = (unsigned)__builtin_amdgcn_update_dpp((int)hi, (int)hi, CTRL, ROW_MASK, 0xF, false);
    const unsigned long long p = ((unsigned long long)phi << 32) | plo;
    return p < x ? p : x;
}

// ---------------------------------------------------------------------------
// Kernel 2: JV LSA, one wave per batch. Round-8 (= r7 with compile fix):
//  - no serial L2-prefetch (r6 regression)
//  - cross-lane argmin via DPP min-reduce + readlane broadcasts
//  - r6 tournament tree + p[best] tracking (passed bit-exact)
// ---------------------------------------------------------------------------
__global__ __launch_bounds__(64) void lsa_kernel(
    const float* __restrict__ costT,  // [B,M,N]
    int* __restrict__ out)            // rows [B,M] then cols [B,M], int32
{
    const int b    = blockIdx.x;
    const int lane = threadIdx.x;

    __shared__ double s_u[MM + 1];
    __shared__ int    s_p[NN + 1];
    __shared__ int    s_way[NN + 1];
    __shared__ int    s_c4r[MM];

    double v[NSLOT], minv[NSLOT];
    int    preg[NSLOT];
    float  cv[NSLOT];

    for (int j = lane; j <= NN; j += 64) s_p[j] = 0;
    for (int i = lane; i <= MM; i += 64) s_u[i] = 0.0;
    #pragma unroll
    for (int s = 0; s < NSLOT; ++s) { v[s] = 0.0; preg[s] = 0; }
    __syncthreads();

    const float* cb = costT + (size_t)b * MM * NN;

    // prefetch row 0 (Dijkstra i=1)
    #pragma unroll
    for (int s = 0; s < NSLOT; ++s) {
        const bool valid = (s < NSLOT - 1) || (lane < LAST_VALID);
        cv[s] = valid ? cb[s * 64 + lane] : 0.f;
    }

    for (int i = 1; i <= MM; ++i) {
        unsigned used_mask = 0;
        #pragma unroll
        for (int s = 0; s < NSLOT; ++s) minv[s] = BIG;
        if (lane == 0) s_p[0] = i;
        int j0 = 0;
        double ui0 = 0.0;   // u[i] == 0: fresh row never touched before

        while (true) {
            // mark j0 used (column 0 is virtual)
            if (j0 > 0) {
                const int jp = j0 - 1;
                if ((jp & 63) == lane) used_mask |= 1u << (jp >> 6);
            }

            // ---- scan: update minv/way, build per-slot candidates
            double cnd[NSLOT];
            #pragma unroll
            for (int s = 0; s < NSLOT; ++s) {
                const bool valid = (s < NSLOT - 1) || (lane < LAST_VALID);
                const bool fr = valid && !((used_mask >> s) & 1u);
                const double cur = (double)cv[s] - ui0 - v[s];
                if (fr && cur < minv[s]) { minv[s] = cur; s_way[s * 64 + lane + 1] = j0; }
                cnd[s] = fr ? minv[s] : BIG;
            }
            // ---- tournament tree (depth 4), left (= smaller j) wins ties
            double n1v[8]; int n1j[8], n1p[8];
            #pragma unroll
            for (int s = 0; s < 8; ++s) {
                const int a = 2 * s, bb2 = 2 * s + 1;
                double va = cnd[a]; int ja = a * 64 + lane + 1; int pa = preg[a];
                if (bb2 < NSLOT) {
                    if (cnd[bb2] < va) { va = cnd[bb2]; ja = bb2 * 64 + lane + 1; pa = preg[bb2]; }
                }
                n1v[s] = va; n1j[s] = ja; n1p[s] = pa;
            }
            double n2v[4]; int n2j[4], n2p[4];
            #pragma unroll
            for (int s = 0; s < 4; ++s) {
                double va = n1v[2*s]; int ja = n1j[2*s]; int pa = n1p[2*s];
                if (n1v[2*s+1] < va) { va = n1v[2*s+1]; ja = n1j[2*s+1]; pa = n1p[2*s+1]; }
                n2v[s] = va; n2j[s] = ja; n2p[s] = pa;
            }
            double n3v[2]; int n3j[2], n3p[2];
            #pragma unroll
            for (int s = 0; s < 2; ++s) {
                double va = n2v[2*s]; int ja = n2j[2*s]; int pa = n2p[2*s];
                if (n2v[2*s+1] < va) { va = n2v[2*s+1]; ja = n2j[2*s+1]; pa = n2p[2*s+1]; }
                n3v[s] = va; n3j[s] = ja; n3p[s] = pa;
            }
            double bv = n3v[0]; int bj = n3j[0]; int bp = n3p[0];
            if (n3v[1] < bv) { bv = n3v[1]; bj = n3j[1]; bp = n3p[1]; }

            // ---- sortable-u64 key (+0.0 normalizes -0 so key== iff double==)
            const double bvn = bv + 0.0;
            const long long xb = __double_as_longlong(bvn);
            const unsigned long long mykey =
                (xb < 0) ? ~(unsigned long long)xb
                         : ((unsigned long long)xb | 0x8000000000000000ULL);

            // ---- DPP wave-min (lane 63 accumulates), then SGPR broadcast
            unsigned long long kr = mykey;
            kr = dpp_min_u64<0xB1,  0xF>(kr);   // quad_perm [1,0,3,2]  (xor1)
            kr = dpp_min_u64<0x4E,  0xF>(kr);   // quad_perm [2,3,0,1]  (xor2)
            kr = dpp_min_u64<0x141, 0xF>(kr);   // row_half_mirror      (xor4)
            kr = dpp_min_u64<0x140, 0xF>(kr);   // row_mirror           (xor8)
            kr = dpp_min_u64<0x142, 0xA>(kr);   // row_bcast15 -> rows 1,3
            kr = dpp_min_u64<0x143, 0xC>(kr);   // row_bcast31 -> rows 2,3
            const unsigned klo = (unsigned)__builtin_amdgcn_readlane((int)(unsigned)kr, 63);
            const unsigned khi = (unsigned)__builtin_amdgcn_readlane((int)(kr >> 32), 63);
            const unsigned long long kmin = ((unsigned long long)khi << 32) | klo;

            const unsigned long long inv =
                (kmin & 0x8000000000000000ULL) ? (kmin ^ 0x8000000000000000ULL) : ~kmin;
            const double delta = __longlong_as_double((long long)inv);

            // ---- j1 and p[j1]: owner lane via ballot, broadcast via readlane
            const unsigned long long tied = __ballot(mykey == kmin);
            int j1, pj1;
            if (__builtin_popcountll(tied) == 1) {
                const int src = (int)__builtin_ctzll(tied);
                j1  = __builtin_amdgcn_readlane(bj, src);
                pj1 = __builtin_amdgcn_readlane(bp, src);
            } else {
                int cand = (mykey == kmin) ? bj : 0x7fffffff;
                #pragma unroll
                for (int m = 1; m < 64; m <<= 1) {
                    const int oc = __shfl_xor(cand, m);
                    if (oc < cand) cand = oc;
                }
                j1 = cand;
                const unsigned long long own = __ballot(mykey == kmin && bj == j1);
                pj1 = __builtin_amdgcn_readlane(bp, (int)__builtin_ctzll(own));
            }

            // issue next-row loads ASAP; s_u read + updates hide under them
            double ui_next = 0.0;
            if (pj1 != 0) {
                const float* crow = cb + (size_t)(pj1 - 1) * NN;
                #pragma unroll
                for (int s = 0; s < NSLOT; ++s) {
                    const bool valid = (s < NSLOT - 1) || (lane < LAST_VALID);
                    if (valid) cv[s] = crow[s * 64 + lane];
                }
                ui_next = s_u[pj1];
            }

            // dual updates (sequential-rounding order identical to reference)
            if (lane == 0) s_u[i] += delta;      // u[p[0]] = u[i]
            double uval[NSLOT];
            #pragma unroll
            for (int s = 0; s < NSLOT; ++s) {
                const bool valid = (s < NSLOT - 1) || (lane < LAST_VALID);
                if (valid && ((used_mask >> s) & 1u)) uval[s] = s_u[preg[s]];
            }
            #pragma unroll
            for (int s = 0; s < NSLOT; ++s) {
                const bool valid = (s < NSLOT - 1) || (lane < LAST_VALID);
                if (valid) {
                    if ((used_mask >> s) & 1u) {
                        s_u[preg[s]] = uval[s] + delta;
                        v[s] -= delta;
                    } else {
                        minv[s] -= delta;
                    }
                }
            }

            if (pj1 == 0) {
                if (lane == 0) {                 // augment along 'way' chain
                    int ja = j1;
                    while (ja) {
                        const int jb = s_way[ja];
                        s_p[ja] = s_p[jb];
                        ja = jb;
                    }
                }
                break;
            }
            j0 = j1; ui0 = ui_next;
        }

        // refresh cached p[j] for this lane's columns
        #pragma unroll
        for (int s = 0; s < NSLOT; ++s) {
            const bool valid = (s < NSLOT - 1) || (lane < LAST_VALID);
            if (valid) preg[s] = s_p[s * 64 + lane + 1];
        }
        // prefetch first row of next Dijkstra (cost row index = i, 0-based)
        if (i < MM) {
            const float* crow = cb + (size_t)i * NN;
            #pragma unroll
            for (int s = 0; s < NSLOT; ++s) {
                const bool valid = (s < NSLOT - 1) || (lane < LAST_VALID);
                if (valid) cv[s] = crow[s * 64 + lane];
            }
        }
    }

    // col4row: target t -> matched pred index
    for (int j = 1 + lane; j <= NN; j += 64) {
        const int pj = s_p[j];
        if (pj > 0) s_c4r[pj - 1] = j - 1;
    }
    __syncthreads();

    // transposed return: rows = sorted pred indices, cols = target permutation
    for (int t = lane; t < MM; t += 64) {
        const int val = s_c4r[t];
        int rank = 0;
        for (int q = 0; q < MM; ++q) rank += (s_c4r[q] < val);
        out[(size_t)b * MM + rank] = val;
        out[(size_t)BB * MM + (size_t)b * MM + rank] = t;
    }
}

extern "C" void kernel_launch(void* const* d_in, const int* in_sizes, int n_in,
                              void* d_out, int out_size, void* d_ws, size_t ws_size,
                              hipStream_t stream) {
    const float* logits  = (const float*)d_in[0];   // [64,900,91] f32
    const float* boxes   = (const float*)d_in[1];   // [64,900,4]  f32
    const int*   tlabels = (const int*)d_in[2];     // [64,128]    i32 (from i64)
    const float* tboxes  = (const float*)d_in[3];   // [64,128,4]  f32
    int*   out   = (int*)d_out;                     // rows[64,128] ++ cols[64,128]
    float* costT = (float*)d_ws;                    // [64,128,900] f32 = 28.1 MB

    dim3 g1((NN + TPB_C - 1) / TPB_C, BB);          // 8 x 64
    cost_kernel<<<g1, TPB_C, 0, stream>>>(logits, boxes, tlabels, tboxes, costT);
    lsa_kernel<<<BB, 64, 0, stream>>>(costT, out);
}

// Round 9
// 435.890 us; speedup vs baseline: 1.3540x; 1.0843x over previous
//
#include <hip/hip_runtime.h>
#include <hip/hip_bf16.h>
#include <float.h>

#define BB 64
#define NN 900
#define CC 91
#define MM 128
#define BIG 1e18
#define DINF __builtin_huge_val()
#define NSLOT 15              // 15*64 = 960 >= 900 columns per lane-slot grid
#define LAST_VALID 4          // slot 14 valid for lanes 0..3 (896+lane < 900)
#define TPB_C 128

// ---------------------------------------------------------------------------
// Kernel 1: cost matrix, stored TRANSPOSED as costT[b][t (M)][p (N)] f32.
// Unchanged from round-3/5/8 passing version.
// ---------------------------------------------------------------------------
__global__ __launch_bounds__(TPB_C) void cost_kernel(
    const float* __restrict__ logits,   // [B,N,C]
    const float* __restrict__ boxes,    // [B,N,4]
    const int*   __restrict__ tlabels,  // [B,M]
    const float* __restrict__ tboxes,   // [B,M,4]
    float* __restrict__ costT)          // [B,M,N]
{
    const int b   = blockIdx.y;
    const int p0  = blockIdx.x * TPB_C;
    const int cnt = min(TPB_C, NN - p0);
    const int tid = threadIdx.x;

    __shared__ float s_lg[TPB_C * CC];   // 46592 B
    __shared__ float s_tb[MM][4];
    __shared__ int   s_tl[MM];

    {
        s_tl[tid] = tlabels[b * MM + tid];
        const float4 tb4 = ((const float4*)tboxes)[(size_t)b * MM + tid];
        s_tb[tid][0] = tb4.x; s_tb[tid][1] = tb4.y;
        s_tb[tid][2] = tb4.z; s_tb[tid][3] = tb4.w;
    }
    {
        const float* gbase = logits + ((size_t)b * NN + p0) * CC;
        const int total = cnt * CC;
        const int n4 = total >> 2;
        for (int k = tid; k < n4; k += TPB_C)
            ((float4*)s_lg)[k] = ((const float4*)gbase)[k];
        for (int k = (n4 << 2) + tid; k < total; k += TPB_C)
            s_lg[k] = gbase[k];
    }
    __syncthreads();
    if (tid >= cnt) return;

    const float* lg = s_lg + tid * CC;
    float mx = -INFINITY;
    for (int c = 0; c < CC; ++c) mx = fmaxf(mx, lg[c]);
    float ssum = 0.f;
    for (int c = 0; c < CC; ++c) ssum += expf(lg[c] - mx);

    const float4 bx4 = ((const float4*)boxes)[(size_t)b * NN + p0 + tid];
    const float cx = bx4.x, cy = bx4.y, w = bx4.z, h = bx4.w;
    const float px0 = cx - 0.5f * w, py0 = cy - 0.5f * h;
    const float px1 = cx + 0.5f * w, py1 = cy + 0.5f * h;
    const float parea = (px1 - px0) * (py1 - py0);

    float* outp = costT + (size_t)b * MM * NN + p0 + tid;
    for (int j = 0; j < MM; ++j) {
        const float tcx = s_tb[j][0], tcy = s_tb[j][1], tw = s_tb[j][2], th = s_tb[j][3];
        float l1 = ((fabsf(cx - tcx) + fabsf(cy - tcy)) + fabsf(w - tw)) + fabsf(h - th);
        const float tx0 = tcx - 0.5f * tw, ty0 = tcy - 0.5f * th;
        const float tx1 = tcx + 0.5f * tw, ty1 = tcy + 0.5f * th;
        float iw = fminf(px1, tx1) - fmaxf(px0, tx0); iw = fmaxf(iw, 0.f);
        float ih = fminf(py1, ty1) - fmaxf(py0, ty0); ih = fmaxf(ih, 0.f);
        const float inter = iw * ih;
        const float tarea = (tx1 - tx0) * (ty1 - ty0);
        const float uni   = parea + tarea - inter;
        const float iou   = inter / (uni + 1e-6f);
        const float enc   = (fmaxf(px1, tx1) - fminf(px0, tx0)) *
                            (fmaxf(py1, ty1) - fminf(py0, ty0)) + 1e-6f;
        const float giou  = iou - (enc - uni) / enc;
        const float pcls  = expf(lg[s_tl[j]] - mx) / ssum;
        const float cost  = (1.0f * (-pcls) + 5.0f * l1) + 2.0f * (-giou);
        outp[(size_t)j * NN] = cost;
    }
}

// ---------------------------------------------------------------------------
// DPP helpers (literal-constant template args; rocPRIM reduce pattern;
// min lands in lane 63). Masked rows keep their own value (old = self).
// ---------------------------------------------------------------------------
template<int CTRL, int ROW_MASK>
__device__ __forceinline__ unsigned dpp_min_u32_step(unsigned x) {
    const unsigned m = (unsigned)__builtin_amdgcn_update_dpp((int)x, (int)x, CTRL, ROW_MASK, 0xF, false);
    return m < x ? m : x;
}
__device__ __forceinline__ unsigned wave_min_u32(unsigned x) {
    x = dpp_min_u32_step<0xB1,  0xF>(x);  // quad_perm xor1
    x = dpp_min_u32_step<0x4E,  0xF>(x);  // quad_perm xor2
    x = dpp_min_u32_step<0x141, 0xF>(x);  // row_half_mirror
    x = dpp_min_u32_step<0x140, 0xF>(x);  // row_mirror
    x = dpp_min_u32_step<0x142, 0xA>(x);  // row_bcast15 -> rows 1,3
    x = dpp_min_u32_step<0x143, 0xC>(x);  // row_bcast31 -> rows 2,3
    return (unsigned)__builtin_amdgcn_readlane((int)x, 63);
}
__device__ __forceinline__ int d_hi(double d) { return (int)(__double_as_longlong(d) >> 32); }
__device__ __forceinline__ int d_lo(double d) { return (int)__double_as_longlong(d); }
__device__ __forceinline__ double mk_d(int hi, int lo) {
    return __longlong_as_double(((long long)hi << 32) | (unsigned long long)(unsigned)lo);
}

// ---------------------------------------------------------------------------
// Kernel 2: JV LSA, one wave per batch. Round-9:
//  - hi-word v_min_u32 DPP fast-path argmin (lo/payload DPP only on hi-ties)
//  - payload (j<<18 | way<<8 | p) through the tree: no s_way array, no LDS
//    reads on the selection chain
//  - used slots -> minv=+inf inside unconditional minv-=delta
//  - register path list: u-updates via lanes 0..T (3 instrs), augment via
//    ballot/readlane register chase (LDS spill fallback for paths > 63)
// Reference f64 op order / rounding / argmin tie-breaks preserved exactly.
// ---------------------------------------------------------------------------
__global__ __launch_bounds__(64) void lsa_kernel(
    const float* __restrict__ costT,  // [B,M,N]
    int* __restrict__ out)            // rows [B,M] then cols [B,M], int32
{
    const int b    = blockIdx.x;
    const int lane = threadIdx.x;

    __shared__ double s_u[MM + 1];
    __shared__ int    s_p[NN + 1];
    __shared__ int    s_c4r[MM];
    __shared__ int    s_spill[3 * (NN + 2)];   // pathological path spill

    double v[NSLOT], minv[NSLOT];
    unsigned pay[NSLOT], pay_base[NSLOT];
    float  cv[NSLOT];

    for (int j = lane; j <= NN; j += 64) s_p[j] = 0;
    for (int i = lane; i <= MM; i += 64) s_u[i] = 0.0;
    #pragma unroll
    for (int s = 0; s < NSLOT; ++s) {
        v[s] = 0.0;
        pay_base[s] = ((unsigned)(s * 64 + lane + 1) << 18);  // p=0 initially
        pay[s] = pay_base[s];
    }
    __syncthreads();

    const float* cb = costT + (size_t)b * MM * NN;

    // prefetch row 0 (Dijkstra i=1)
    #pragma unroll
    for (int s = 0; s < NSLOT; ++s) {
        const bool valid = (s < NSLOT - 1) || (lane < LAST_VALID);
        cv[s] = valid ? cb[s * 64 + lane] : 0.f;
    }

    for (int i = 1; i <= MM; ++i) {
        unsigned used_mask = 0;
        #pragma unroll
        for (int s = 0; s < NSLOT; ++s) minv[s] = BIG;

        int T = 0;                 // iteration index within this Dijkstra
        int curj0 = 0;             // column being marked used this iteration
        int curi0 = i;             // p[curj0] (row); virtual col 0 -> row i
        int curway = 0;            // way[curj0] snapshot (frozen at selection)
        int nspill = 0;
        double ui0 = 0.0;          // u[i]==0: fresh row never touched before
        int my_j0 = -1, my_i0 = 0, my_way = 0;   // path entry owned by lane T

        while (true) {
            // record path entry T
            if (T < 63) {
                if (lane == T) { my_j0 = curj0; my_i0 = curi0; my_way = curway; }
            } else {
                if (lane == 0) {
                    s_spill[3 * nspill]     = curj0;
                    s_spill[3 * nspill + 1] = curi0;
                    s_spill[3 * nspill + 2] = curway;
                }
                ++nspill;
            }
            // mark curj0 used (column 0 is virtual)
            if (curj0 > 0) {
                const int jp = curj0 - 1;
                if ((jp & 63) == lane) used_mask |= 1u << (jp >> 6);
            }

            // ---- scan: fr-guarded improvement of (minv, payload)
            const unsigned pay_or = (unsigned)curj0 << 8;
            #pragma unroll
            for (int s = 0; s < NSLOT; ++s) {
                const bool valid = (s < NSLOT - 1) || (lane < LAST_VALID);
                const bool fr = valid && !((used_mask >> s) & 1u);
                const double cur = ((double)cv[s] - ui0) - v[s];
                const bool imp = fr && (cur < minv[s]);
                if (imp) { minv[s] = cur; pay[s] = pay_base[s] | pay_or; }
            }

            // ---- per-lane tournament tree (depth 4), left (smaller j) wins ties
            double n1v[8]; unsigned n1p[8];
            #pragma unroll
            for (int s = 0; s < 8; ++s) {
                const int a = 2 * s, c = 2 * s + 1;
                double va = minv[a]; unsigned pa = pay[a];
                if (c < NSLOT) { if (minv[c] < va) { va = minv[c]; pa = pay[c]; } }
                n1v[s] = va; n1p[s] = pa;
            }
            double n2v[4]; unsigned n2p[4];
            #pragma unroll
            for (int s = 0; s < 4; ++s) {
                double va = n1v[2*s]; unsigned pa = n1p[2*s];
                if (n1v[2*s+1] < va) { va = n1v[2*s+1]; pa = n1p[2*s+1]; }
                n2v[s] = va; n2p[s] = pa;
            }
            double n3v[2]; unsigned n3p[2];
            #pragma unroll
            for (int s = 0; s < 2; ++s) {
                double va = n2v[2*s]; unsigned pa = n2p[2*s];
                if (n2v[2*s+1] < va) { va = n2v[2*s+1]; pa = n2p[2*s+1]; }
                n3v[s] = va; n3p[s] = pa;
            }
            double bv = n3v[0]; unsigned bpay = n3p[0];
            if (n3v[1] < bv) { bv = n3v[1]; bpay = n3p[1]; }

            // ---- cross-lane argmin: hi-word DPP fast path
            const double bvn = bv + 0.0;               // -0 -> +0
            const int hi = d_hi(bvn);
            const int sm = hi >> 31;
            const unsigned th = (unsigned)(hi ^ (sm | 0x80000000));
            const unsigned minhi = wave_min_u32(th);

            const unsigned long long hit = __ballot(th == minhi);
            unsigned wpay; double delta;
            if (__builtin_popcountll(hit) == 1) {
                const int src = (int)__builtin_ctzll(hit);
                wpay  = (unsigned)__builtin_amdgcn_readlane((int)bpay, src);
                delta = mk_d(__builtin_amdgcn_readlane(hi, src),
                             __builtin_amdgcn_readlane(d_lo(bvn), src));
            } else {
                const unsigned tl = (unsigned)(d_lo(bvn) ^ sm);
                const unsigned minlo = wave_min_u32((th == minhi) ? tl : 0xFFFFFFFFu);
                const bool full = (th == minhi) && (tl == minlo);
                wpay = wave_min_u32(full ? bpay : 0xFFFFFFFFu);  // min payload = min j
                const int src = (int)__builtin_ctzll(__ballot(full));
                delta = mk_d(__builtin_amdgcn_readlane(hi, src),
                             __builtin_amdgcn_readlane(d_lo(bvn), src));
            }
            const int j1   = (int)(wpay >> 18);
            const int way1 = (int)((wpay >> 8) & 0x3FF);
            const int pj1  = (int)(wpay & 0xFF);

            // issue next-row loads ASAP; s_u read + updates hide under them
            double ui_next = 0.0;
            if (pj1 != 0) {
                const float* crow = cb + (size_t)(pj1 - 1) * NN;
                #pragma unroll
                for (int s = 0; s < NSLOT; ++s) {
                    const bool valid = (s < NSLOT - 1) || (lane < LAST_VALID);
                    if (valid) cv[s] = crow[s * 64 + lane];
                }
                ui_next = s_u[pj1];
            }

            // ---- u-updates: rows of used columns are distinct -> parallel RMW
            if (T < 63) {
                if (lane <= T) s_u[my_i0] += delta;
            } else {
                if (lane == 0) s_u[i] += delta;     // col-0 entry
                double uval[NSLOT];
                #pragma unroll
                for (int s = 0; s < NSLOT; ++s) {
                    const bool valid = (s < NSLOT - 1) || (lane < LAST_VALID);
                    if (valid && ((used_mask >> s) & 1u))
                        uval[s] = s_u[pay_base[s] & 0xFF];
                }
                #pragma unroll
                for (int s = 0; s < NSLOT; ++s) {
                    const bool valid = (s < NSLOT - 1) || (lane < LAST_VALID);
                    if (valid && ((used_mask >> s) & 1u))
                        s_u[pay_base[s] & 0xFF] = uval[s] + delta;
                }
            }
            // ---- v / minv updates (per-iteration rounding kept)
            #pragma unroll
            for (int s = 0; s < NSLOT; ++s) {
                const bool valid = (s < NSLOT - 1) || (lane < LAST_VALID);
                if (valid) {
                    const bool ub = (used_mask >> s) & 1u;
                    v[s]    = ub ? v[s] - delta : v[s];
                    minv[s] = ub ? DINF : minv[s] - delta;
                }
            }

            if (pj1 == 0) {
                // ---- augment via register chase (scalar, divergence-free)
                int ja = j1, jb = way1;
                const int cap = (T < 63) ? T : 62;
                while (jb != 0) {
                    int np, nw;
                    const unsigned long long bal = __ballot(lane <= cap && my_j0 == jb);
                    if (bal != 0) {
                        const int src = (int)__builtin_ctzll(bal);
                        np = __builtin_amdgcn_readlane(my_i0, src);
                        nw = __builtin_amdgcn_readlane(my_way, src);
                    } else {  // pathological: search LDS spill (uniform reads)
                        np = 0; nw = 0;
                        for (int k = 0; k < nspill; ++k) {
                            if (s_spill[3 * k] == jb) {
                                np = s_spill[3 * k + 1];
                                nw = s_spill[3 * k + 2];
                                break;
                            }
                        }
                    }
                    if (lane == 0) s_p[ja] = np;
                    ja = jb; jb = nw;
                }
                if (lane == 0) s_p[ja] = i;   // terminal: p[ja] = p[0] = i
                break;
            }
            curj0 = j1; curi0 = pj1; curway = way1; ui0 = ui_next; ++T;
        }

        // refresh cached p[j] (payload base) for this lane's columns
        #pragma unroll
        for (int s = 0; s < NSLOT; ++s) {
            const bool valid = (s < NSLOT - 1) || (lane < LAST_VALID);
            if (valid) {
                const int j = s * 64 + lane + 1;
                pay_base[s] = ((unsigned)j << 18) | (unsigned)s_p[j];
            }
        }
        // prefetch first row of next Dijkstra (cost row index = i, 0-based)
        if (i < MM) {
            const float* crow = cb + (size_t)i * NN;
            #pragma unroll
            for (int s = 0; s < NSLOT; ++s) {
                const bool valid = (s < NSLOT - 1) || (lane < LAST_VALID);
                if (valid) cv[s] = crow[s * 64 + lane];
            }
        }
    }

    // col4row: target t -> matched pred index
    for (int j = 1 + lane; j <= NN; j += 64) {
        const int pj = s_p[j];
        if (pj > 0) s_c4r[pj - 1] = j - 1;
    }
    __syncthreads();

    // transposed return: rows = sorted pred indices, cols = target permutation
    for (int t = lane; t < MM; t += 64) {
        const int val = s_c4r[t];
        int rank = 0;
        for (int q = 0; q < MM; ++q) rank += (s_c4r[q] < val);
        out[(size_t)b * MM + rank] = val;
        out[(size_t)BB * MM + (size_t)b * MM + rank] = t;
    }
}

extern "C" void kernel_launch(void* const* d_in, const int* in_sizes, int n_in,
                              void* d_out, int out_size, void* d_ws, size_t ws_size,
                              hipStream_t stream) {
    const float* logits  = (const float*)d_in[0];   // [64,900,91] f32
    const float* boxes   = (const float*)d_in[1];   // [64,900,4]  f32
    const int*   tlabels = (const int*)d_in[2];     // [64,128]    i32 (from i64)
    const float* tboxes  = (const float*)d_in[3];   // [64,128,4]  f32
    int*   out   = (int*)d_out;                     // rows[64,128] ++ cols[64,128]
    float* costT = (float*)d_ws;                    // [64,128,900] f32 = 28.1 MB

    dim3 g1((NN + TPB_C - 1) / TPB_C, BB);          // 8 x 64
    cost_kernel<<<g1, TPB_C, 0, stream>>>(logits, boxes, tlabels, tboxes, costT);
    lsa_kernel<<<BB, 64, 0, stream>>>(costT, out);
}